// Round 7
// baseline (49.262 us; speedup 1.0000x reference)
//
#include <hip/hip_runtime.h>

// out[k,i,l] = sum_{j<l} w[i,j]*x[k,j] + bias[i]
// B=128, N_h=512, size_in=1024.
// R7: each wave processes 4 rows sharing one w-row (same i, k=k0..k0+3).
// Per chunk: 1 w-chunk load + 4 x-chunk loads -> L2 read traffic -37%
// (20B/lane/row vs 32), and the 4 wave-scans run interleaved (ILP).
// Block = 4 waves = 4 consecutive i (shares the 4 x-rows via L1).
// Grid = (128/4 k-groups) x (512/4 i-groups) = 4096 blocks.

#define SIZE_IN 1024
#define N_H 512

typedef float f32x4 __attribute__((ext_vector_type(4)));

template <int CTRL, int ROW_MASK>
__device__ __forceinline__ float dpp_add(float x) {
    int moved = __builtin_amdgcn_update_dpp(0, __float_as_int(x), CTRL,
                                            ROW_MASK, 0xf, true);
    return x + __int_as_float(moved);
}

__global__ __launch_bounds__(256) void nade_kernel(
    const float* __restrict__ x,     // [B, SIZE_IN]
    const float* __restrict__ w,     // [N_H, SIZE_IN]
    const float* __restrict__ bias,  // [N_H]
    float* __restrict__ out)         // [B, N_H, SIZE_IN]
{
    const int lane = threadIdx.x & 63;
    const int wave = threadIdx.x >> 6;
    const int ib = blockIdx.x & 127;          // i-group (512/4 = 128)
    const int kb = blockIdx.x >> 7;           // k-group (128/4 = 32)
    const int i  = ib * 4 + wave;             // this wave's head index
    const int k0 = kb * 4;                    // first of 4 batch rows

    const float* wr = w + (size_t)i * SIZE_IN;
    const float* xr = x + (size_t)k0 * SIZE_IN;               // +r*SIZE_IN
    float* outr = out + (size_t)(k0 * N_H + i) * SIZE_IN;     // +r*N_H*SIZE_IN
    const float b = bias[i];

    float carry[4] = {b, b, b, b};
#pragma unroll
    for (int c = 0; c < 4; ++c) {
        const int j0 = c * 256 + lane * 4;
        const f32x4 wv = *reinterpret_cast<const f32x4*>(wr + j0);

        float p0[4], p1[4], p2[4], p3[4], s[4];
#pragma unroll
        for (int r = 0; r < 4; ++r) {
            const f32x4 xv = *reinterpret_cast<const f32x4*>(xr + r * SIZE_IN + j0);
            p0[r] = xv.x * wv.x;
            p1[r] = p0[r] + xv.y * wv.y;
            p2[r] = p1[r] + xv.z * wv.z;
            p3[r] = p2[r] + xv.w * wv.w;
            s[r]  = p3[r];
        }

        // 4 independent 6-round DPP scans, interleaved for ILP
#pragma unroll
        for (int r = 0; r < 4; ++r) s[r] = dpp_add<0x111, 0xf>(s[r]); // shr:1
#pragma unroll
        for (int r = 0; r < 4; ++r) s[r] = dpp_add<0x112, 0xf>(s[r]); // shr:2
#pragma unroll
        for (int r = 0; r < 4; ++r) s[r] = dpp_add<0x114, 0xf>(s[r]); // shr:4
#pragma unroll
        for (int r = 0; r < 4; ++r) s[r] = dpp_add<0x118, 0xf>(s[r]); // shr:8
#pragma unroll
        for (int r = 0; r < 4; ++r) s[r] = dpp_add<0x142, 0xa>(s[r]); // bcast:15
#pragma unroll
        for (int r = 0; r < 4; ++r) s[r] = dpp_add<0x143, 0xc>(s[r]); // bcast:31

#pragma unroll
        for (int r = 0; r < 4; ++r) {
            const float excl = carry[r] + (s[r] - p3[r]);
            f32x4 ov;
            ov.x = excl;
            ov.y = excl + p0[r];
            ov.z = excl + p1[r];
            ov.w = excl + p2[r];
            *reinterpret_cast<f32x4*>(outr + (size_t)r * (N_H * SIZE_IN) + j0) = ov;
            carry[r] += __int_as_float(
                __builtin_amdgcn_readlane(__float_as_int(s[r]), 63));
        }
    }
}

extern "C" void kernel_launch(void* const* d_in, const int* in_sizes, int n_in,
                              void* d_out, int out_size, void* d_ws, size_t ws_size,
                              hipStream_t stream) {
    const float* x    = (const float*)d_in[0];
    const float* w    = (const float*)d_in[1];
    const float* bias = (const float*)d_in[2];
    float* out = (float*)d_out;

    const int B = in_sizes[0] / SIZE_IN;       // 128
    const int blocks = (B / 4) * (N_H / 4);    // 4096
    nade_kernel<<<blocks, 256, 0, stream>>>(x, w, bias, out);
}

// Round 8
// 45.142 us; speedup vs baseline: 1.0913x; 1.0913x over previous
//
#include <hip/hip_runtime.h>

// out[k,i,l] = sum_{j<l} w[i,j]*x[k,j] + bias[i]
// B=128, N_h=512, size_in=1024.
// One 64-lane wave per output row (k,i). Lane owns 4 consecutive floats per
// 256-element chunk -> float4 coalesced loads/stores (1KB/instr).
// FINAL (R5 restored — best measured: 45.12 us, ~95% of achievable HBM rate).
// Ablation history: DPP scan (-1.7us WIN, R5); launch_bounds cap (null, R6);
// 4-rows/wave read-reduction (regressed +4.1us, R7); nt stores (regressed, R3).

#define SIZE_IN 1024
#define N_H 512

typedef float f32x4 __attribute__((ext_vector_type(4)));

template <int CTRL, int ROW_MASK>
__device__ __forceinline__ float dpp_add(float x) {
    // x += DPP-moved(x); masked-off / out-of-bounds lanes contribute 0.
    int moved = __builtin_amdgcn_update_dpp(0, __float_as_int(x), CTRL,
                                            ROW_MASK, 0xf, true);
    return x + __int_as_float(moved);
}

__device__ __forceinline__ float wave_incl_scan(float x) {
    x = dpp_add<0x111, 0xf>(x);  // row_shr:1
    x = dpp_add<0x112, 0xf>(x);  // row_shr:2
    x = dpp_add<0x114, 0xf>(x);  // row_shr:4
    x = dpp_add<0x118, 0xf>(x);  // row_shr:8
    x = dpp_add<0x142, 0xa>(x);  // row_bcast:15 -> rows 1,3
    x = dpp_add<0x143, 0xc>(x);  // row_bcast:31 -> rows 2,3
    return x;
}

__global__ __launch_bounds__(256) void nade_kernel(
    const float* __restrict__ x,     // [B, SIZE_IN]
    const float* __restrict__ w,     // [N_H, SIZE_IN]
    const float* __restrict__ bias,  // [N_H]
    float* __restrict__ out)         // [B, N_H, SIZE_IN]
{
    const int lane = threadIdx.x & 63;
    const int wave = threadIdx.x >> 6;
    const int row  = blockIdx.x * 4 + wave;   // row = k*N_H + i
    const int k = row >> 9;                   // row / N_H
    const int i = row & (N_H - 1);            // row % N_H

    const float* xr = x + (size_t)k * SIZE_IN;
    const float* wr = w + (size_t)i * SIZE_IN;
    float* outr = out + (size_t)row * SIZE_IN;

    float carry = bias[i];                    // bias folded into the carry
#pragma unroll
    for (int c = 0; c < 4; ++c) {
        const int j0 = c * 256 + lane * 4;
        const f32x4 xv = *reinterpret_cast<const f32x4*>(xr + j0);
        const f32x4 wv = *reinterpret_cast<const f32x4*>(wr + j0);
        // in-lane inclusive prefix of the 4 products
        const float p0 = xv.x * wv.x;
        const float p1 = p0 + xv.y * wv.y;
        const float p2 = p1 + xv.z * wv.z;
        const float p3 = p2 + xv.w * wv.w;
        // wave-wide inclusive scan of per-lane sums (6 DPP adds, no DS)
        const float s = wave_incl_scan(p3);
        const float excl = carry + (s - p3);  // exclusive prefix at lane start
        f32x4 ov;
        ov.x = excl;
        ov.y = excl + p0;
        ov.z = excl + p1;
        ov.w = excl + p2;
        *reinterpret_cast<f32x4*>(outr + j0) = ov;
        // chunk total = lane 63's inclusive value (wave-uniform via readlane)
        carry += __int_as_float(__builtin_amdgcn_readlane(__float_as_int(s), 63));
    }
}

extern "C" void kernel_launch(void* const* d_in, const int* in_sizes, int n_in,
                              void* d_out, int out_size, void* d_ws, size_t ws_size,
                              hipStream_t stream) {
    const float* x    = (const float*)d_in[0];
    const float* w    = (const float*)d_in[1];
    const float* bias = (const float*)d_in[2];
    float* out = (float*)d_out;

    const int B = in_sizes[0] / SIZE_IN;      // 128
    const int rows = B * N_H;                  // 65536
    const int blocks = rows / 4;               // 4 waves/block, 1 row/wave

    nade_kernel<<<blocks, 256, 0, stream>>>(x, w, bias, out);
}